// Round 1
// baseline (1753.315 us; speedup 1.0000x reference)
//
#include <hip/hip_runtime.h>
#include <hip/hip_bf16.h>

// MemoryAttention: L=2 decoder layers on MI355X.
// B=8, S=512, M=4096, D=256, H=8, dh=32, DFF=2048.
// fp32 in/out, bf16 MFMA internal (tolerance 9.8e-2 budgets for this).

#define NTOK 4096            // B*S
#define NMEM 32768           // B*M
#define DMODEL 256
#define DFF_ 2048

typedef __attribute__((ext_vector_type(8))) short bf16x8;
typedef __attribute__((ext_vector_type(4))) float f32x4;

__device__ __forceinline__ unsigned short f2bf(float f) {
  return __builtin_bit_cast(unsigned short, __float2bfloat16(f));
}

// ---------------- elementwise: o = a + s*b ----------------
__global__ __launch_bounds__(256) void add_kernel(const float* __restrict__ a,
                                                  const float* __restrict__ b,
                                                  float s, float* __restrict__ o, int n4) {
  int i = blockIdx.x * blockDim.x + threadIdx.x;
  int st = gridDim.x * blockDim.x;
  for (; i < n4; i += st) {
    float4 va = ((const float4*)a)[i];
    float4 vb = ((const float4*)b)[i];
    float4 r;
    r.x = va.x + s * vb.x; r.y = va.y + s * vb.y;
    r.z = va.z + s * vb.z; r.w = va.w + s * vb.w;
    ((float4*)o)[i] = r;
  }
}

// o = x + scale * emb[batch][d]   (emb is (8,256) for this layer; scale is device scalar)
__global__ __launch_bounds__(256) void enh_kernel(const float* __restrict__ x,
                                                  const float* __restrict__ emb,
                                                  const float* __restrict__ sp,
                                                  float* __restrict__ o, int n4) {
  float s = sp[0];
  int i = blockIdx.x * blockDim.x + threadIdx.x;
  int st = gridDim.x * blockDim.x;
  for (; i < n4; i += st) {
    int base = i << 2;
    int b = base >> 17;            // / (512*256)
    int d = base & 255;
    float4 vx = ((const float4*)x)[i];
    float4 ve = *(const float4*)&emb[b * 256 + d];
    float4 r;
    r.x = vx.x + s * ve.x; r.y = vx.y + s * ve.y;
    r.z = vx.z + s * ve.z; r.w = vx.w + s * ve.w;
    ((float4*)o)[i] = r;
  }
}

// ---------------- layernorm, D=256, one block(256 thr)/row ----------------
__global__ __launch_bounds__(256) void ln_kernel(const float* __restrict__ x,
                                                 const float* __restrict__ g,
                                                 const float* __restrict__ b,
                                                 float* __restrict__ y) {
  int row = blockIdx.x, t = threadIdx.x;
  float v = x[(size_t)row * 256 + t];
  float s = v;
#pragma unroll
  for (int off = 32; off; off >>= 1) s += __shfl_xor(s, off);
  __shared__ float r1[4], r2[4];
  int wid = t >> 6, lane = t & 63;
  if (!lane) r1[wid] = s;
  __syncthreads();
  float mean = (r1[0] + r1[1] + r1[2] + r1[3]) * (1.f / 256.f);
  float d = v - mean;
  float q = d * d;
#pragma unroll
  for (int off = 32; off; off >>= 1) q += __shfl_xor(q, off);
  if (!lane) r2[wid] = q;
  __syncthreads();
  float var = (r2[0] + r2[1] + r2[2] + r2[3]) * (1.f / 256.f);
  y[(size_t)row * 256 + t] = d * rsqrtf(var + 1e-5f) * g[t] + b[t];
}

// ---------------- GEMM: C[N,M] = A[N,K] @ W[M,K]^T (+bias)(+relu)(+resid) ----------------
// 128x128 block tile, 4 waves (each 64x64 = 4x4 mfma frags), BK=32, bf16 LDS staging.
#define LDSP 40   // padded LDS row stride (bf16 elems): 80B -> spreads banks, keeps 16B align

__global__ __launch_bounds__(256) void gemm_kernel(const float* __restrict__ A,
                                                   const float* __restrict__ W,
                                                   const float* __restrict__ bias,
                                                   const float* __restrict__ resid,
                                                   float* __restrict__ C,
                                                   int N, int M, int K, int relu) {
  __shared__ __align__(16) unsigned short As[128 * LDSP];
  __shared__ __align__(16) unsigned short Ws[128 * LDSP];
  int tid = threadIdx.x;
  int lane = tid & 63, w = tid >> 6;
  int l15 = lane & 15, lg = lane >> 4;
  int n0 = blockIdx.y * 128, m0 = blockIdx.x * 128;
  int wr = (w >> 1) * 64, wc = (w & 1) * 64;
  f32x4 acc[4][4] = {};
  for (int k0 = 0; k0 < K; k0 += 32) {
    __syncthreads();
#pragma unroll
    for (int i = 0; i < 4; ++i) {
      int idx = tid + i * 256;
      int row = idx >> 3, kv = (idx & 7) << 2;
      float4 va = *(const float4*)&A[(size_t)(n0 + row) * K + k0 + kv];
      ushort4 sa;
      sa.x = f2bf(va.x); sa.y = f2bf(va.y); sa.z = f2bf(va.z); sa.w = f2bf(va.w);
      *(ushort4*)&As[row * LDSP + kv] = sa;
      float4 vw = *(const float4*)&W[(size_t)(m0 + row) * K + k0 + kv];
      ushort4 sw;
      sw.x = f2bf(vw.x); sw.y = f2bf(vw.y); sw.z = f2bf(vw.z); sw.w = f2bf(vw.w);
      *(ushort4*)&Ws[row * LDSP + kv] = sw;
    }
    __syncthreads();
    bf16x8 af[4], wf[4];
#pragma unroll
    for (int f = 0; f < 4; ++f) {
      af[f] = *(const bf16x8*)&As[(wr + f * 16 + l15) * LDSP + lg * 8];
      wf[f] = *(const bf16x8*)&Ws[(wc + f * 16 + l15) * LDSP + lg * 8];
    }
#pragma unroll
    for (int fm = 0; fm < 4; ++fm)
#pragma unroll
      for (int fn = 0; fn < 4; ++fn)
        acc[fm][fn] = __builtin_amdgcn_mfma_f32_16x16x32_bf16(af[fm], wf[fn], acc[fm][fn], 0, 0, 0);
  }
#pragma unroll
  for (int fm = 0; fm < 4; ++fm)
#pragma unroll
    for (int fn = 0; fn < 4; ++fn)
#pragma unroll
      for (int r = 0; r < 4; ++r) {
        int row = n0 + wr + fm * 16 + lg * 4 + r;
        int col = m0 + wc + fn * 16 + l15;
        float v = acc[fm][fn][r];
        if (bias) v += bias[col];
        if (relu) v = fmaxf(v, 0.f);
        if (resid) v += resid[(size_t)row * M + col];
        C[(size_t)row * M + col] = v;
      }
}

// ---------------- fused flash attention ----------------
// grid (Sq/64, H, B); 4 waves/block, each wave owns a 16-query tile; dh=32.
// QK^T: one mfma per 16-key half (K-dim = 32 = dh). Online softmax (16-lane shfl
// reductions). P goes D-layout -> LDS -> A-layout. PV: 2 mfmas per 32-key chunk.
// img != null => cross-object mask: skip 32-key chunks whose key-batch image
// differs from the query-batch image (the +1.0 same-image bias is uniform within
// each admissible row set, so it cancels in softmax; -1e9 entries are exact 0).
__global__ __launch_bounds__(256) void attn_kernel(const float* __restrict__ Q,
                                                   const float* __restrict__ Kp,
                                                   const float* __restrict__ V,
                                                   float* __restrict__ O,
                                                   int ldq, int ldk, int ldv, int ldo,
                                                   int Sq, int Sk,
                                                   const int* __restrict__ img,
                                                   float scale) {
  __shared__ __align__(16) unsigned short P[4][16 * 40];
  int tid = threadIdx.x, lane = tid & 63, w = tid >> 6;
  int l15 = lane & 15, lg = lane >> 4;
  int h = blockIdx.y, b = blockIdx.z;
  int q_tile = blockIdx.x * 64 + w * 16;
  const float* Qb = Q + (size_t)b * Sq * ldq + h * 32;
  const float* Kb = Kp + (size_t)b * Sk * ldk + h * 32;
  const float* Vb = V + (size_t)b * Sk * ldv + h * 32;
  float* Ob = O + (size_t)b * Sq * ldo + h * 32;

  bf16x8 qf;  // Q pre-scaled by 1/sqrt(dh)
  {
    const float* qp = Qb + (size_t)(q_tile + l15) * ldq + lg * 8;
    float4 a = *(const float4*)qp;
    float4 c = *(const float4*)(qp + 4);
    qf[0] = (short)f2bf(a.x * scale); qf[1] = (short)f2bf(a.y * scale);
    qf[2] = (short)f2bf(a.z * scale); qf[3] = (short)f2bf(a.w * scale);
    qf[4] = (short)f2bf(c.x * scale); qf[5] = (short)f2bf(c.y * scale);
    qf[6] = (short)f2bf(c.z * scale); qf[7] = (short)f2bf(c.w * scale);
  }
  float m[4] = {-1e30f, -1e30f, -1e30f, -1e30f};
  float l[4] = {0.f, 0.f, 0.f, 0.f};
  f32x4 o0 = {}, o1 = {};
  int qimg = 0;
  if (img) qimg = img[q_tile >> 9];
  int nc = Sk >> 5;
  for (int c = 0; c < nc; ++c) {
    if (img && img[c >> 4] != qimg) continue;  // (c*32)/512 — uniform across block
    // K fragments (rows = keys, contiguous dh reads)
    bf16x8 kf0, kf1;
    {
      const float* kp = Kb + (size_t)((c << 5) + l15) * ldk + lg * 8;
      float4 a = *(const float4*)kp;
      float4 d = *(const float4*)(kp + 4);
      kf0[0] = (short)f2bf(a.x); kf0[1] = (short)f2bf(a.y);
      kf0[2] = (short)f2bf(a.z); kf0[3] = (short)f2bf(a.w);
      kf0[4] = (short)f2bf(d.x); kf0[5] = (short)f2bf(d.y);
      kf0[6] = (short)f2bf(d.z); kf0[7] = (short)f2bf(d.w);
      const float* kp2 = kp + (size_t)16 * ldk;
      float4 e = *(const float4*)kp2;
      float4 f = *(const float4*)(kp2 + 4);
      kf1[0] = (short)f2bf(e.x); kf1[1] = (short)f2bf(e.y);
      kf1[2] = (short)f2bf(e.z); kf1[3] = (short)f2bf(e.w);
      kf1[4] = (short)f2bf(f.x); kf1[5] = (short)f2bf(f.y);
      kf1[6] = (short)f2bf(f.z); kf1[7] = (short)f2bf(f.w);
    }
    f32x4 z = {};
    f32x4 s0 = __builtin_amdgcn_mfma_f32_16x16x32_bf16(qf, kf0, z, 0, 0, 0);
    f32x4 s1 = __builtin_amdgcn_mfma_f32_16x16x32_bf16(qf, kf1, z, 0, 0, 0);
    // online softmax update (rows = lg*4+r, cols = l15 / l15+16)
    float p0[4], p1[4];
#pragma unroll
    for (int r = 0; r < 4; ++r) {
      float cm = fmaxf(s0[r], s1[r]);
      cm = fmaxf(cm, __shfl_xor(cm, 1));
      cm = fmaxf(cm, __shfl_xor(cm, 2));
      cm = fmaxf(cm, __shfl_xor(cm, 4));
      cm = fmaxf(cm, __shfl_xor(cm, 8));
      float mn = fmaxf(m[r], cm);
      float sf = __expf(m[r] - mn);
      p0[r] = __expf(s0[r] - mn);
      p1[r] = __expf(s1[r] - mn);
      float rs = p0[r] + p1[r];
      rs += __shfl_xor(rs, 1);
      rs += __shfl_xor(rs, 2);
      rs += __shfl_xor(rs, 4);
      rs += __shfl_xor(rs, 8);
      l[r] = l[r] * sf + rs;
      m[r] = mn;
      o0[r] *= sf;
      o1[r] *= sf;
    }
    // P: D-layout -> per-wave LDS -> A-layout
    unsigned short* pw = P[w];
#pragma unroll
    for (int r = 0; r < 4; ++r) {
      pw[(lg * 4 + r) * 40 + l15] = f2bf(p0[r]);
      pw[(lg * 4 + r) * 40 + l15 + 16] = f2bf(p1[r]);
    }
    __syncthreads();
    bf16x8 pf = *(const bf16x8*)&pw[l15 * 40 + lg * 8];
    // V fragments: column reads (scalar; optimize later)
    const float* vp = Vb + (size_t)((c << 5) + lg * 8) * ldv + l15;
    bf16x8 vf0, vf1;
#pragma unroll
    for (int i = 0; i < 8; ++i) {
      vf0[i] = (short)f2bf(vp[(size_t)i * ldv]);
      vf1[i] = (short)f2bf(vp[(size_t)i * ldv + 16]);
    }
    o0 = __builtin_amdgcn_mfma_f32_16x16x32_bf16(pf, vf0, o0, 0, 0, 0);
    o1 = __builtin_amdgcn_mfma_f32_16x16x32_bf16(pf, vf1, o1, 0, 0, 0);
  }
#pragma unroll
  for (int r = 0; r < 4; ++r) {
    float inv = 1.f / l[r];
    int row = q_tile + lg * 4 + r;
    Ob[(size_t)row * ldo + l15] = o0[r] * inv;
    Ob[(size_t)row * ldo + l15 + 16] = o1[r] * inv;
  }
}

// ---------------- orchestration ----------------
extern "C" void kernel_launch(void* const* d_in, const int* in_sizes, int n_in,
                              void* d_out, int out_size, void* d_ws, size_t ws_size,
                              hipStream_t stream) {
  const float* curr       = (const float*)d_in[0];
  const float* memory     = (const float*)d_in[1];
  const float* curr_pos   = (const float*)d_in[2];
  const float* memory_pos = (const float*)d_in[3];
  const int*   img_ids    = (const int*)d_in[4];
  const float* sa_w_in  = (const float*)d_in[5];
  const float* sa_b_in  = (const float*)d_in[6];
  const float* sa_w_out = (const float*)d_in[7];
  const float* sa_b_out = (const float*)d_in[8];
  const float* co_w_in  = (const float*)d_in[9];
  const float* co_b_in  = (const float*)d_in[10];
  const float* co_w_out = (const float*)d_in[11];
  const float* co_b_out = (const float*)d_in[12];
  const float* ca_w_in  = (const float*)d_in[13];
  const float* ca_b_in  = (const float*)d_in[14];
  const float* ca_w_out = (const float*)d_in[15];
  const float* ca_b_out = (const float*)d_in[16];
  const float* obj_emb  = (const float*)d_in[17];
  const float* obj_scale= (const float*)d_in[18];
  const float* n1_g = (const float*)d_in[19];
  const float* n1_b = (const float*)d_in[20];
  const float* n2_g = (const float*)d_in[21];
  const float* n2_b = (const float*)d_in[22];
  const float* n3_g = (const float*)d_in[23];
  const float* n3_b = (const float*)d_in[24];
  const float* w1 = (const float*)d_in[25];
  const float* b1 = (const float*)d_in[26];
  const float* w2 = (const float*)d_in[27];
  const float* b2 = (const float*)d_in[28];
  const float* norm_g = (const float*)d_in[29];
  const float* norm_b = (const float*)d_in[30];
  float* out = (float*)d_out;

  float* ws   = (float*)d_ws;
  float* x    = ws;                      // 4096*256
  float* t2   = x + NTOK * DMODEL;       // 4096*256 (LN out / enhanced)
  float* qkv  = t2 + NTOK * DMODEL;      // 4096*768 (also CA q-proj 4096*256)
  float* att  = qkv + NTOK * 3 * DMODEL; // 4096*256
  float* memk = att + NTOK * DMODEL;     // 32768*256 (persists)
  float* kbuf = memk + (size_t)NMEM * DMODEL; // 32768*256
  float* vbuf = kbuf + (size_t)NMEM * DMODEL; // 32768*256
  float* hbuf = kbuf;                    // 4096*2048 alias (kbuf dead during MLP)

  const float scale = 0.17677669529663687f;  // 1/sqrt(32)

  auto gemm = [&](const float* A, const float* W, const float* bias,
                  const float* resid, float* C, int N, int M, int K, int relu) {
    dim3 g(M / 128, N / 128);
    gemm_kernel<<<g, 256, 0, stream>>>(A, W, bias, resid, C, N, M, K, relu);
  };

  // x = curr + 0.1*curr_pos ; memk = memory + memory_pos
  add_kernel<<<1024, 256, 0, stream>>>(curr, curr_pos, 0.1f, x, NTOK * DMODEL / 4);
  add_kernel<<<2048, 256, 0, stream>>>(memory, memory_pos, 1.0f, memk, NMEM * DMODEL / 4);

  for (int l = 0; l < 2; ++l) {
    const size_t wi = (size_t)l * 3 * DMODEL * DMODEL;   // 196608
    const size_t wo = (size_t)l * DMODEL * DMODEL;       // 65536
    // ---- self-attention ----
    ln_kernel<<<NTOK, 256, 0, stream>>>(x, n1_g + l * DMODEL, n1_b + l * DMODEL, t2);
    gemm(t2, sa_w_in + wi, sa_b_in + l * 3 * DMODEL, nullptr, qkv, NTOK, 3 * DMODEL, DMODEL, 0);
    attn_kernel<<<dim3(8, 8, 8), 256, 0, stream>>>(qkv, qkv + 256, qkv + 512, att,
                                                   768, 768, 768, 256, 512, 512, nullptr, scale);
    gemm(att, sa_w_out + wo, sa_b_out + l * DMODEL, x, x, NTOK, DMODEL, DMODEL, 0);
    // ---- cross-object attention (flattened 4096 tokens, image-block mask) ----
    enh_kernel<<<1024, 256, 0, stream>>>(x, obj_emb + l * 8 * DMODEL, obj_scale + l,
                                         t2, NTOK * DMODEL / 4);
    gemm(t2, co_w_in + wi, co_b_in + l * 3 * DMODEL, nullptr, qkv, NTOK, 3 * DMODEL, DMODEL, 0);
    attn_kernel<<<dim3(64, 8, 1), 256, 0, stream>>>(qkv, qkv + 256, qkv + 512, att,
                                                    768, 768, 768, 256, 4096, 4096, img_ids, scale);
    gemm(att, co_w_out + wo, co_b_out + l * DMODEL, x, x, NTOK, DMODEL, DMODEL, 0);
    // ---- cross-attention to memory ----
    ln_kernel<<<NTOK, 256, 0, stream>>>(x, n2_g + l * DMODEL, n2_b + l * DMODEL, t2);
    gemm(t2, ca_w_in + wi, ca_b_in + l * 3 * DMODEL, nullptr, qkv, NTOK, DMODEL, DMODEL, 0);
    gemm(memk, ca_w_in + wi + DMODEL * DMODEL, ca_b_in + l * 3 * DMODEL + DMODEL,
         nullptr, kbuf, NMEM, DMODEL, DMODEL, 0);
    gemm(memory, ca_w_in + wi + 2 * DMODEL * DMODEL, ca_b_in + l * 3 * DMODEL + 2 * DMODEL,
         nullptr, vbuf, NMEM, DMODEL, DMODEL, 0);
    attn_kernel<<<dim3(8, 8, 8), 256, 0, stream>>>(qkv, kbuf, vbuf, att,
                                                   256, 256, 256, 256, 512, 4096, nullptr, scale);
    gemm(att, ca_w_out + wo, ca_b_out + l * DMODEL, x, x, NTOK, DMODEL, DMODEL, 0);
    // ---- MLP ----
    ln_kernel<<<NTOK, 256, 0, stream>>>(x, n3_g + l * DMODEL, n3_b + l * DMODEL, t2);
    gemm(t2, w1 + (size_t)l * DFF_ * DMODEL, b1 + l * DFF_, nullptr, hbuf, NTOK, DFF_, DMODEL, 1);
    gemm(hbuf, w2 + (size_t)l * DMODEL * DFF_, b2 + l * DMODEL, x, x, NTOK, DMODEL, DFF_, 0);
  }
  ln_kernel<<<NTOK, 256, 0, stream>>>(x, norm_g, norm_b, out);
}

// Round 2
// 1307.217 us; speedup vs baseline: 1.3413x; 1.3413x over previous
//
#include <hip/hip_runtime.h>
#include <hip/hip_bf16.h>

// MemoryAttention: L=2 decoder layers on MI355X.
// B=8, S=512, M=4096, D=256, H=8, dh=32, DFF=2048.
// fp32 in/out, bf16 MFMA internal.

#define NTOK 4096            // B*S
#define NMEM 32768           // B*M
#define DMODEL 256
#define DFF_ 2048

typedef __attribute__((ext_vector_type(8))) short bf16x8;
typedef __attribute__((ext_vector_type(4))) short bf16x4;
typedef __attribute__((ext_vector_type(4))) float f32x4;

__device__ __forceinline__ unsigned short f2bf(float f) {
  return __builtin_bit_cast(unsigned short, __float2bfloat16(f));
}

// ---------------- elementwise: o = a + s*b ----------------
__global__ __launch_bounds__(256) void add_kernel(const float* __restrict__ a,
                                                  const float* __restrict__ b,
                                                  float s, float* __restrict__ o, int n4) {
  int i = blockIdx.x * blockDim.x + threadIdx.x;
  int st = gridDim.x * blockDim.x;
  for (; i < n4; i += st) {
    float4 va = ((const float4*)a)[i];
    float4 vb = ((const float4*)b)[i];
    float4 r;
    r.x = va.x + s * vb.x; r.y = va.y + s * vb.y;
    r.z = va.z + s * vb.z; r.w = va.w + s * vb.w;
    ((float4*)o)[i] = r;
  }
}

// o = x + scale * emb[batch][d]
__global__ __launch_bounds__(256) void enh_kernel(const float* __restrict__ x,
                                                  const float* __restrict__ emb,
                                                  const float* __restrict__ sp,
                                                  float* __restrict__ o, int n4) {
  float s = sp[0];
  int i = blockIdx.x * blockDim.x + threadIdx.x;
  int st = gridDim.x * blockDim.x;
  for (; i < n4; i += st) {
    int base = i << 2;
    int b = base >> 17;
    int d = base & 255;
    float4 vx = ((const float4*)x)[i];
    float4 ve = *(const float4*)&emb[b * 256 + d];
    float4 r;
    r.x = vx.x + s * ve.x; r.y = vx.y + s * ve.y;
    r.z = vx.z + s * ve.z; r.w = vx.w + s * ve.w;
    ((float4*)o)[i] = r;
  }
}

// ---------------- layernorm, D=256, one block(256 thr)/row ----------------
__global__ __launch_bounds__(256) void ln_kernel(const float* __restrict__ x,
                                                 const float* __restrict__ g,
                                                 const float* __restrict__ b,
                                                 float* __restrict__ y) {
  int row = blockIdx.x, t = threadIdx.x;
  float v = x[(size_t)row * 256 + t];
  float s = v;
#pragma unroll
  for (int off = 32; off; off >>= 1) s += __shfl_xor(s, off);
  __shared__ float r1[4], r2[4];
  int wid = t >> 6, lane = t & 63;
  if (!lane) r1[wid] = s;
  __syncthreads();
  float mean = (r1[0] + r1[1] + r1[2] + r1[3]) * (1.f / 256.f);
  float d = v - mean;
  float q = d * d;
#pragma unroll
  for (int off = 32; off; off >>= 1) q += __shfl_xor(q, off);
  if (!lane) r2[wid] = q;
  __syncthreads();
  float var = (r2[0] + r2[1] + r2[2] + r2[3]) * (1.f / 256.f);
  y[(size_t)row * 256 + t] = d * rsqrtf(var + 1e-5f) * g[t] + b[t];
}

// ---------------- GEMM: C[N,M] = A[N,K] @ W[M,K]^T (+bias)(+relu)(+resid) ----------------
#define LDSP 40

__global__ __launch_bounds__(256) void gemm_kernel(const float* __restrict__ A,
                                                   const float* __restrict__ W,
                                                   const float* __restrict__ bias,
                                                   const float* __restrict__ resid,
                                                   float* __restrict__ C,
                                                   int N, int M, int K, int relu) {
  __shared__ __align__(16) unsigned short As[128 * LDSP];
  __shared__ __align__(16) unsigned short Ws[128 * LDSP];
  int tid = threadIdx.x;
  int lane = tid & 63, w = tid >> 6;
  int l15 = lane & 15, lg = lane >> 4;
  int n0 = blockIdx.y * 128, m0 = blockIdx.x * 128;
  int wr = (w >> 1) * 64, wc = (w & 1) * 64;
  f32x4 acc[4][4] = {};
  for (int k0 = 0; k0 < K; k0 += 32) {
    __syncthreads();
#pragma unroll
    for (int i = 0; i < 4; ++i) {
      int idx = tid + i * 256;
      int row = idx >> 3, kv = (idx & 7) << 2;
      float4 va = *(const float4*)&A[(size_t)(n0 + row) * K + k0 + kv];
      ushort4 sa;
      sa.x = f2bf(va.x); sa.y = f2bf(va.y); sa.z = f2bf(va.z); sa.w = f2bf(va.w);
      *(ushort4*)&As[row * LDSP + kv] = sa;
      float4 vw = *(const float4*)&W[(size_t)(m0 + row) * K + k0 + kv];
      ushort4 sw;
      sw.x = f2bf(vw.x); sw.y = f2bf(vw.y); sw.z = f2bf(vw.z); sw.w = f2bf(vw.w);
      *(ushort4*)&Ws[row * LDSP + kv] = sw;
    }
    __syncthreads();
    bf16x8 af[4], wf[4];
#pragma unroll
    for (int f = 0; f < 4; ++f) {
      af[f] = *(const bf16x8*)&As[(wr + f * 16 + l15) * LDSP + lg * 8];
      wf[f] = *(const bf16x8*)&Ws[(wc + f * 16 + l15) * LDSP + lg * 8];
    }
#pragma unroll
    for (int fm = 0; fm < 4; ++fm)
#pragma unroll
      for (int fn = 0; fn < 4; ++fn)
        acc[fm][fn] = __builtin_amdgcn_mfma_f32_16x16x32_bf16(af[fm], wf[fn], acc[fm][fn], 0, 0, 0);
  }
#pragma unroll
  for (int fm = 0; fm < 4; ++fm)
#pragma unroll
    for (int fn = 0; fn < 4; ++fn)
#pragma unroll
      for (int r = 0; r < 4; ++r) {
        int row = n0 + wr + fm * 16 + lg * 4 + r;
        int col = m0 + wc + fn * 16 + l15;
        float v = acc[fm][fn][r];
        if (bias) v += bias[col];
        if (relu) v = fmaxf(v, 0.f);
        if (resid) v += resid[(size_t)row * M + col];
        C[(size_t)row * M + col] = v;
      }
}

// ---------------- fused flash attention (v2) ----------------
// 1-D grid, XCD-bijective remap; work id = (b*H + h)*nqt + qt so all q-tiles
// of one (b,h) land on one XCD (K/V <= 2MB fits per-XCD L2).
// Block = 4 waves, 64 queries; wave owns 16 queries. KVBLK=64 keys staged in
// LDS per chunk: Ks[64][KP] row-major bf16, Vt[32][VP] transposed bf16.
// Swapped QK^T: S^T = mfma_16x16x32(A=K, B=Q) -> lane l15 = query, rows
// (lg*4+r) = keys: softmax is lane-local over 16 regs + shfl_xor(16,32).
// PV: swapped-QK D-layout IS the 16x16x16 A-fragment layout -> no P
// redistribution; B-frag = vector ds_read_b64 from Vt.
#define KVBLK 64
#define KP 40    // Ks stride (bf16): 80B rows -> balanced bank groups for b128
#define VP 68    // Vt stride (bf16): 136B rows -> balanced for b64, 8B aligned

__global__ __launch_bounds__(256) void attn_kernel(const float* __restrict__ Q,
                                                   const float* __restrict__ Kp,
                                                   const float* __restrict__ V,
                                                   float* __restrict__ O,
                                                   int ldq, int ldk, int ldv, int ldo,
                                                   int Sq, int Sk, int nqt,
                                                   const int* __restrict__ img,
                                                   float scale) {
  __shared__ __align__(16) unsigned short Ks[KVBLK * KP];
  __shared__ __align__(16) unsigned short Vt[32 * VP];
  int tid = threadIdx.x, lane = tid & 63, w = tid >> 6;
  int l15 = lane & 15, lg = lane >> 4;
  // XCD-bijective block remap (gridDim.x % 8 == 0 always here)
  int u = blockIdx.x;
  int wid = (u & 7) * (gridDim.x >> 3) + (u >> 3);
  int qt = wid % nqt;
  int h = (wid / nqt) & 7;
  int b = wid / (nqt * 8);
  int q_tile = qt * 64 + w * 16;

  const float* Qb = Q + (size_t)b * Sq * ldq + h * 32;
  const float* Kb = Kp + (size_t)b * Sk * ldk + h * 32;
  const float* Vb = V + (size_t)b * Sk * ldv + h * 32;
  float* Ob = O + (size_t)b * Sq * ldo + h * 32;

  // chunk admissibility bitmask (nc <= 64)
  unsigned long long adm = ~0ull;
  if (img) {
    int qimg = img[(qt * 64) >> 9];
    adm = 0;
#pragma unroll
    for (int j = 0; j < 8; ++j)
      if (img[j] == qimg) adm |= (0xFFull << (8 * j));
  }

  // Q fragment (B-operand): lane n=l15=query, k=d=lg*8+i; pre-scaled.
  bf16x8 qf;
  {
    const float* qp = Qb + (size_t)(q_tile + l15) * ldq + lg * 8;
    float4 a = *(const float4*)qp;
    float4 c = *(const float4*)(qp + 4);
    qf[0] = (short)f2bf(a.x * scale); qf[1] = (short)f2bf(a.y * scale);
    qf[2] = (short)f2bf(a.z * scale); qf[3] = (short)f2bf(a.w * scale);
    qf[4] = (short)f2bf(c.x * scale); qf[5] = (short)f2bf(c.y * scale);
    qf[6] = (short)f2bf(c.z * scale); qf[7] = (short)f2bf(c.w * scale);
  }

  float m_ = -1e30f, l_ = 0.f;
  f32x4 o0 = {}, o1 = {};
  int nc = Sk / KVBLK;
  for (int c = 0; c < nc; ++c) {
    if (!((adm >> c) & 1)) continue;   // uniform across block
    int c0 = c * KVBLK;
    __syncthreads();   // LDS free (previous chunk's reads drained)
    // ---- stage K (row-major bf16) and V (transposed bf16) ----
#pragma unroll
    for (int it = 0; it < 2; ++it) {
      int i = tid + it * 256;
      int row = i >> 3;            // 0..63 key
      int dcol = (i & 7) << 2;     // 0,4,...,28
      float4 kv = *(const float4*)(Kb + (size_t)(c0 + row) * ldk + dcol);
      ushort4 ksv;
      ksv.x = f2bf(kv.x); ksv.y = f2bf(kv.y); ksv.z = f2bf(kv.z); ksv.w = f2bf(kv.w);
      *(ushort4*)&Ks[row * KP + dcol] = ksv;
      float4 vv = *(const float4*)(Vb + (size_t)(c0 + row) * ldv + dcol);
      Vt[(dcol + 0) * VP + row] = f2bf(vv.x);
      Vt[(dcol + 1) * VP + row] = f2bf(vv.y);
      Vt[(dcol + 2) * VP + row] = f2bf(vv.z);
      Vt[(dcol + 3) * VP + row] = f2bf(vv.w);
    }
    __syncthreads();
    // ---- QK^T (swapped): 4 tiles of 16 keys ----
    f32x4 st[4];
    f32x4 z = {};
#pragma unroll
    for (int t = 0; t < 4; ++t) {
      bf16x8 kf = *(const bf16x8*)&Ks[(t * 16 + l15) * KP + lg * 8];
      st[t] = __builtin_amdgcn_mfma_f32_16x16x32_bf16(kf, qf, z, 0, 0, 0);
    }
    // ---- online softmax (lane-local + 2 shfl per reduce) ----
    float cm = st[0][0];
#pragma unroll
    for (int t = 0; t < 4; ++t)
#pragma unroll
      for (int r = 0; r < 4; ++r) cm = fmaxf(cm, st[t][r]);
    cm = fmaxf(cm, __shfl_xor(cm, 16));
    cm = fmaxf(cm, __shfl_xor(cm, 32));
    float mn = fmaxf(m_, cm);
    float sf = __expf(m_ - mn);
    m_ = mn;
    float p[4][4];
    float rs = 0.f;
#pragma unroll
    for (int t = 0; t < 4; ++t)
#pragma unroll
      for (int r = 0; r < 4; ++r) {
        float e = __expf(st[t][r] - mn);
        p[t][r] = e;
        rs += e;
      }
    rs += __shfl_xor(rs, 16);
    rs += __shfl_xor(rs, 32);
    l_ = l_ * sf + rs;
#pragma unroll
    for (int r = 0; r < 4; ++r) {
      float s4 = __shfl(sf, lg * 4 + r);
      o0[r] *= s4;
      o1[r] *= s4;
    }
    // ---- PV: 4x mfma_16x16x16 per d-half; A=P is already in-layout ----
#pragma unroll
    for (int t = 0; t < 4; ++t) {
      bf16x4 pa;
      pa[0] = (short)f2bf(p[t][0]); pa[1] = (short)f2bf(p[t][1]);
      pa[2] = (short)f2bf(p[t][2]); pa[3] = (short)f2bf(p[t][3]);
      bf16x4 v0 = *(const bf16x4*)&Vt[l15 * VP + t * 16 + lg * 4];
      bf16x4 v1 = *(const bf16x4*)&Vt[(16 + l15) * VP + t * 16 + lg * 4];
      o0 = __builtin_amdgcn_mfma_f32_16x16x16bf16_1k(pa, v0, o0, 0, 0, 0);
      o1 = __builtin_amdgcn_mfma_f32_16x16x16bf16_1k(pa, v1, o1, 0, 0, 0);
    }
  }
  // ---- epilogue: rows = q = lg*4+r, cols = d = l15 / 16+l15 ----
#pragma unroll
  for (int r = 0; r < 4; ++r) {
    float lr = __shfl(l_, lg * 4 + r);
    float inv = 1.f / lr;
    int row = q_tile + lg * 4 + r;
    Ob[(size_t)row * ldo + l15] = o0[r] * inv;
    Ob[(size_t)row * ldo + l15 + 16] = o1[r] * inv;
  }
}

// ---------------- orchestration ----------------
extern "C" void kernel_launch(void* const* d_in, const int* in_sizes, int n_in,
                              void* d_out, int out_size, void* d_ws, size_t ws_size,
                              hipStream_t stream) {
  const float* curr       = (const float*)d_in[0];
  const float* memory     = (const float*)d_in[1];
  const float* curr_pos   = (const float*)d_in[2];
  const float* memory_pos = (const float*)d_in[3];
  const int*   img_ids    = (const int*)d_in[4];
  const float* sa_w_in  = (const float*)d_in[5];
  const float* sa_b_in  = (const float*)d_in[6];
  const float* sa_w_out = (const float*)d_in[7];
  const float* sa_b_out = (const float*)d_in[8];
  const float* co_w_in  = (const float*)d_in[9];
  const float* co_b_in  = (const float*)d_in[10];
  const float* co_w_out = (const float*)d_in[11];
  const float* co_b_out = (const float*)d_in[12];
  const float* ca_w_in  = (const float*)d_in[13];
  const float* ca_b_in  = (const float*)d_in[14];
  const float* ca_w_out = (const float*)d_in[15];
  const float* ca_b_out = (const float*)d_in[16];
  const float* obj_emb  = (const float*)d_in[17];
  const float* obj_scale= (const float*)d_in[18];
  const float* n1_g = (const float*)d_in[19];
  const float* n1_b = (const float*)d_in[20];
  const float* n2_g = (const float*)d_in[21];
  const float* n2_b = (const float*)d_in[22];
  const float* n3_g = (const float*)d_in[23];
  const float* n3_b = (const float*)d_in[24];
  const float* w1 = (const float*)d_in[25];
  const float* b1 = (const float*)d_in[26];
  const float* w2 = (const float*)d_in[27];
  const float* b2 = (const float*)d_in[28];
  const float* norm_g = (const float*)d_in[29];
  const float* norm_b = (const float*)d_in[30];
  float* out = (float*)d_out;

  float* ws   = (float*)d_ws;
  float* x    = ws;
  float* t2   = x + NTOK * DMODEL;
  float* qkv  = t2 + NTOK * DMODEL;
  float* att  = qkv + NTOK * 3 * DMODEL;
  float* memk = att + NTOK * DMODEL;
  float* kbuf = memk + (size_t)NMEM * DMODEL;
  float* vbuf = kbuf + (size_t)NMEM * DMODEL;
  float* hbuf = kbuf;   // alias: kbuf dead during MLP

  const float scale = 0.17677669529663687f;  // 1/sqrt(32)

  auto gemm = [&](const float* A, const float* W, const float* bias,
                  const float* resid, float* C, int N, int M, int K, int relu) {
    dim3 g(M / 128, N / 128);
    gemm_kernel<<<g, 256, 0, stream>>>(A, W, bias, resid, C, N, M, K, relu);
  };

  add_kernel<<<1024, 256, 0, stream>>>(curr, curr_pos, 0.1f, x, NTOK * DMODEL / 4);
  add_kernel<<<2048, 256, 0, stream>>>(memory, memory_pos, 1.0f, memk, NMEM * DMODEL / 4);

  for (int l = 0; l < 2; ++l) {
    const size_t wi = (size_t)l * 3 * DMODEL * DMODEL;
    const size_t wo = (size_t)l * DMODEL * DMODEL;
    // ---- self-attention ----
    ln_kernel<<<NTOK, 256, 0, stream>>>(x, n1_g + l * DMODEL, n1_b + l * DMODEL, t2);
    gemm(t2, sa_w_in + wi, sa_b_in + l * 3 * DMODEL, nullptr, qkv, NTOK, 3 * DMODEL, DMODEL, 0);
    attn_kernel<<<512, 256, 0, stream>>>(qkv, qkv + 256, qkv + 512, att,
                                         768, 768, 768, 256, 512, 512, 8, nullptr, scale);
    gemm(att, sa_w_out + wo, sa_b_out + l * DMODEL, x, x, NTOK, DMODEL, DMODEL, 0);
    // ---- cross-object attention (flattened 4096 tokens, image-block mask) ----
    enh_kernel<<<1024, 256, 0, stream>>>(x, obj_emb + l * 8 * DMODEL, obj_scale + l,
                                         t2, NTOK * DMODEL / 4);
    gemm(t2, co_w_in + wi, co_b_in + l * 3 * DMODEL, nullptr, qkv, NTOK, 3 * DMODEL, DMODEL, 0);
    attn_kernel<<<512, 256, 0, stream>>>(qkv, qkv + 256, qkv + 512, att,
                                         768, 768, 768, 256, 4096, 4096, 64, img_ids, scale);
    gemm(att, co_w_out + wo, co_b_out + l * DMODEL, x, x, NTOK, DMODEL, DMODEL, 0);
    // ---- cross-attention to memory ----
    ln_kernel<<<NTOK, 256, 0, stream>>>(x, n2_g + l * DMODEL, n2_b + l * DMODEL, t2);
    gemm(t2, ca_w_in + wi, ca_b_in + l * 3 * DMODEL, nullptr, qkv, NTOK, DMODEL, DMODEL, 0);
    gemm(memk, ca_w_in + wi + DMODEL * DMODEL, ca_b_in + l * 3 * DMODEL + DMODEL,
         nullptr, kbuf, NMEM, DMODEL, DMODEL, 0);
    gemm(memory, ca_w_in + wi + 2 * DMODEL * DMODEL, ca_b_in + l * 3 * DMODEL + 2 * DMODEL,
         nullptr, vbuf, NMEM, DMODEL, DMODEL, 0);
    attn_kernel<<<512, 256, 0, stream>>>(qkv, kbuf, vbuf, att,
                                         256, 256, 256, 256, 512, 4096, 8, nullptr, scale);
    gemm(att, ca_w_out + wo, ca_b_out + l * DMODEL, x, x, NTOK, DMODEL, DMODEL, 0);
    // ---- MLP ----
    ln_kernel<<<NTOK, 256, 0, stream>>>(x, n3_g + l * DMODEL, n3_b + l * DMODEL, t2);
    gemm(t2, w1 + (size_t)l * DFF_ * DMODEL, b1 + l * DFF_, nullptr, hbuf, NTOK, DFF_, DMODEL, 1);
    gemm(hbuf, w2 + (size_t)l * DMODEL * DFF_, b2 + l * DMODEL, x, x, NTOK, DMODEL, DFF_, 0);
  }
  ln_kernel<<<NTOK, 256, 0, stream>>>(x, norm_g, norm_b, out);
}

// Round 3
// 1083.664 us; speedup vs baseline: 1.6180x; 1.2063x over previous
//
#include <hip/hip_runtime.h>
#include <hip/hip_bf16.h>

// MemoryAttention on MI355X: bf16-resident pipeline.
// B=8, S=512, M=4096, D=256, H=8, dh=32, DFF=2048, L=2.

#define NTOK 4096
#define NMEM 32768
#define DMODEL 256
#define DFF_ 2048

typedef __attribute__((ext_vector_type(8))) short bf16x8;
typedef __attribute__((ext_vector_type(4))) short bf16x4;
typedef __attribute__((ext_vector_type(4))) float f32x4;
typedef unsigned short u16;

__device__ __forceinline__ u16 f2bf(float f) {
  return __builtin_bit_cast(u16, __float2bfloat16(f));
}
__device__ __forceinline__ float bf2f(u16 u) {
  unsigned int x = ((unsigned int)u) << 16;
  return __builtin_bit_cast(float, x);
}
__device__ __forceinline__ void gload16(const u16* g, u16* l) {
  __builtin_amdgcn_global_load_lds(
      (const __attribute__((address_space(1))) unsigned int*)g,
      (__attribute__((address_space(3))) unsigned int*)l, 16, 0, 0);
}

// ---------------- x = a + s*b (f32) ----------------
__global__ __launch_bounds__(256) void add_kernel(const float* __restrict__ a,
                                                  const float* __restrict__ b,
                                                  float s, float* __restrict__ o, int n4) {
  int i = blockIdx.x * blockDim.x + threadIdx.x;
  int st = gridDim.x * blockDim.x;
  for (; i < n4; i += st) {
    float4 va = ((const float4*)a)[i];
    float4 vb = ((const float4*)b)[i];
    float4 r;
    r.x = va.x + s * vb.x; r.y = va.y + s * vb.y;
    r.z = va.z + s * vb.z; r.w = va.w + s * vb.w;
    ((float4*)o)[i] = r;
  }
}

// ---------------- memk = bf16(mem+pos), memv = bf16(mem) ----------------
__global__ __launch_bounds__(256) void memprep_kernel(const float* __restrict__ mem,
                                                      const float* __restrict__ pos,
                                                      u16* __restrict__ memk,
                                                      u16* __restrict__ memv, int n8) {
  int i = blockIdx.x * blockDim.x + threadIdx.x;
  int st = gridDim.x * blockDim.x;
  for (; i < n8; i += st) {
    float4 m0 = ((const float4*)mem)[i * 2], m1 = ((const float4*)mem)[i * 2 + 1];
    float4 p0 = ((const float4*)pos)[i * 2], p1 = ((const float4*)pos)[i * 2 + 1];
    bf16x8 v, k;
    v[0] = (short)f2bf(m0.x); v[1] = (short)f2bf(m0.y);
    v[2] = (short)f2bf(m0.z); v[3] = (short)f2bf(m0.w);
    v[4] = (short)f2bf(m1.x); v[5] = (short)f2bf(m1.y);
    v[6] = (short)f2bf(m1.z); v[7] = (short)f2bf(m1.w);
    k[0] = (short)f2bf(m0.x + p0.x); k[1] = (short)f2bf(m0.y + p0.y);
    k[2] = (short)f2bf(m0.z + p0.z); k[3] = (short)f2bf(m0.w + p0.w);
    k[4] = (short)f2bf(m1.x + p1.x); k[5] = (short)f2bf(m1.y + p1.y);
    k[6] = (short)f2bf(m1.z + p1.z); k[7] = (short)f2bf(m1.w + p1.w);
    *(bf16x8*)(memv + (size_t)i * 8) = v;
    *(bf16x8*)(memk + (size_t)i * 8) = k;
  }
}

// ---------------- weight cast f32 -> bf16 (8 segments) ----------------
struct WArgs { const float* src[8]; int off[8]; int n[8]; };
__global__ __launch_bounds__(256) void wcast_kernel(WArgs a, u16* __restrict__ dst) {
  int st = gridDim.x * blockDim.x;
  for (int j = 0; j < 8; ++j) {
    const float* s = a.src[j];
    u16* d = dst + a.off[j];
    int n8 = a.n[j] >> 3;
    for (int i = blockIdx.x * blockDim.x + threadIdx.x; i < n8; i += st) {
      float4 x0 = ((const float4*)s)[i * 2], x1 = ((const float4*)s)[i * 2 + 1];
      bf16x8 o;
      o[0] = (short)f2bf(x0.x); o[1] = (short)f2bf(x0.y);
      o[2] = (short)f2bf(x0.z); o[3] = (short)f2bf(x0.w);
      o[4] = (short)f2bf(x1.x); o[5] = (short)f2bf(x1.y);
      o[6] = (short)f2bf(x1.z); o[7] = (short)f2bf(x1.w);
      *(bf16x8*)(d + (size_t)i * 8) = o;
    }
  }
}

// ---------------- layernorm D=256; OBF: bf16 or f32 out ----------------
template <int OBF>
__global__ __launch_bounds__(256) void ln_kernel(const float* __restrict__ x,
                                                 const float* __restrict__ g,
                                                 const float* __restrict__ b,
                                                 void* __restrict__ y) {
  int row = blockIdx.x, t = threadIdx.x;
  float v = x[(size_t)row * 256 + t];
  float s = v;
#pragma unroll
  for (int off = 32; off; off >>= 1) s += __shfl_xor(s, off);
  __shared__ float r1[4], r2[4];
  int wid = t >> 6, lane = t & 63;
  if (!lane) r1[wid] = s;
  __syncthreads();
  float mean = (r1[0] + r1[1] + r1[2] + r1[3]) * (1.f / 256.f);
  float d = v - mean;
  float q = d * d;
#pragma unroll
  for (int off = 32; off; off >>= 1) q += __shfl_xor(q, off);
  if (!lane) r2[wid] = q;
  __syncthreads();
  float var = (r2[0] + r2[1] + r2[2] + r2[3]) * (1.f / 256.f);
  float r = d * rsqrtf(var + 1e-5f) * g[t] + b[t];
  if constexpr (OBF) ((u16*)y)[(size_t)row * 256 + t] = f2bf(r);
  else ((float*)y)[(size_t)row * 256 + t] = r;
}

// ---------------- enhanced = x + s*emb[b][d] -> bf16 ----------------
__global__ __launch_bounds__(256) void enh_kernel(const float* __restrict__ x,
                                                  const float* __restrict__ emb,
                                                  const float* __restrict__ sp,
                                                  u16* __restrict__ o, int n4) {
  float s = sp[0];
  int i = blockIdx.x * blockDim.x + threadIdx.x;
  int st = gridDim.x * blockDim.x;
  for (; i < n4; i += st) {
    int base = i << 2;
    int b = base >> 17;
    int d = base & 255;
    float4 vx = ((const float4*)x)[i];
    float4 ve = *(const float4*)&emb[b * 256 + d];
    ushort4 r;
    r.x = f2bf(vx.x + s * ve.x); r.y = f2bf(vx.y + s * ve.y);
    r.z = f2bf(vx.z + s * ve.z); r.w = f2bf(vx.w + s * ve.w);
    *(ushort4*)(o + base) = r;
  }
}

// ---------------- V transpose: out[h][d][tok] = in[tok][col0+h*32+d] ----------------
__global__ __launch_bounds__(256) void transpose_v(const u16* __restrict__ in, int ld,
                                                   int col0, u16* __restrict__ out,
                                                   int ntok) {
  int h = blockIdx.y;
  int tok0 = blockIdx.x * 64;
  int tid = threadIdx.x;
  int d = tid >> 3, g = tid & 7;
  const u16* src = in + col0 + h * 32 + d;
  bf16x8 o;
#pragma unroll
  for (int j = 0; j < 8; ++j) o[j] = (short)src[(size_t)(tok0 + g * 8 + j) * ld];
  *(bf16x8*)(out + (size_t)(h * 32 + d) * ntok + tok0 + g * 8) = o;
}

// ---------------- GEMM 128x128 (4 waves), bf16 A/W, global_load_lds ----------------
template <int CBF>
__global__ __launch_bounds__(256) void gemm128_kernel(const u16* __restrict__ A,
                                                      const u16* __restrict__ W,
                                                      const float* __restrict__ bias,
                                                      const float* __restrict__ resid,
                                                      void* __restrict__ C,
                                                      int N, int M, int K, int relu) {
  __shared__ u16 As[128 * 32];
  __shared__ u16 Ws[128 * 32];
  int tid = threadIdx.x, lane = tid & 63, w = tid >> 6;
  int l15 = lane & 15, lg = lane >> 4;
  int n0 = blockIdx.y * 128, m0 = blockIdx.x * 128;
  int wr = (w >> 1) * 64, wc = (w & 1) * 64;
  const u16* Ag = A + (size_t)(n0 + w * 32 + (lane >> 2)) * K + (lane & 3) * 8;
  const u16* Wg = W + (size_t)(m0 + w * 32 + (lane >> 2)) * K + (lane & 3) * 8;
  u16* Al0 = &As[w * 1024]; u16* Al1 = &As[w * 1024 + 512];
  u16* Wl0 = &Ws[w * 1024]; u16* Wl1 = &Ws[w * 1024 + 512];
  f32x4 acc[4][4] = {};
  for (int k0 = 0; k0 < K; k0 += 32) {
    __syncthreads();
    gload16(Ag + k0, Al0);
    gload16(Ag + (size_t)16 * K + k0, Al1);
    gload16(Wg + k0, Wl0);
    gload16(Wg + (size_t)16 * K + k0, Wl1);
    __syncthreads();
    bf16x8 af[4], wf[4];
#pragma unroll
    for (int f = 0; f < 4; ++f) {
      af[f] = *(const bf16x8*)&As[(wr + f * 16 + l15) * 32 + lg * 8];
      wf[f] = *(const bf16x8*)&Ws[(wc + f * 16 + l15) * 32 + lg * 8];
    }
#pragma unroll
    for (int fm = 0; fm < 4; ++fm)
#pragma unroll
      for (int fn = 0; fn < 4; ++fn)
        acc[fm][fn] = __builtin_amdgcn_mfma_f32_16x16x32_bf16(af[fm], wf[fn], acc[fm][fn], 0, 0, 0);
  }
#pragma unroll
  for (int fm = 0; fm < 4; ++fm)
#pragma unroll
    for (int fn = 0; fn < 4; ++fn)
#pragma unroll
      for (int r = 0; r < 4; ++r) {
        int row = n0 + wr + fm * 16 + lg * 4 + r;
        int col = m0 + wc + fn * 16 + l15;
        float v = acc[fm][fn][r] + bias[col];
        if (relu) v = fmaxf(v, 0.f);
        if constexpr (CBF) {
          ((u16*)C)[(size_t)row * M + col] = f2bf(v);
        } else {
          if (resid) v += resid[(size_t)row * M + col];
          ((float*)C)[(size_t)row * M + col] = v;
        }
      }
}

// ---------------- GEMM 64x64 (1 wave), for small-M grids ----------------
template <int CBF>
__global__ __launch_bounds__(64) void gemm64_kernel(const u16* __restrict__ A,
                                                    const u16* __restrict__ W,
                                                    const float* __restrict__ bias,
                                                    const float* __restrict__ resid,
                                                    void* __restrict__ C,
                                                    int N, int M, int K, int relu) {
  __shared__ u16 As[64 * 32];
  __shared__ u16 Ws[64 * 32];
  int lane = threadIdx.x;
  int l15 = lane & 15, lg = lane >> 4;
  int n0 = blockIdx.y * 64, m0 = blockIdx.x * 64;
  const u16* Ag = A + (size_t)(n0 + (lane >> 2)) * K + (lane & 3) * 8;
  const u16* Wg = W + (size_t)(m0 + (lane >> 2)) * K + (lane & 3) * 8;
  f32x4 acc[4][4] = {};
  for (int k0 = 0; k0 < K; k0 += 32) {
    __syncthreads();
#pragma unroll
    for (int i = 0; i < 4; ++i) {
      gload16(Ag + (size_t)(i * 16) * K + k0, &As[i * 512]);
      gload16(Wg + (size_t)(i * 16) * K + k0, &Ws[i * 512]);
    }
    __syncthreads();
    bf16x8 af[4], wf[4];
#pragma unroll
    for (int f = 0; f < 4; ++f) {
      af[f] = *(const bf16x8*)&As[(f * 16 + l15) * 32 + lg * 8];
      wf[f] = *(const bf16x8*)&Ws[(f * 16 + l15) * 32 + lg * 8];
    }
#pragma unroll
    for (int fm = 0; fm < 4; ++fm)
#pragma unroll
      for (int fn = 0; fn < 4; ++fn)
        acc[fm][fn] = __builtin_amdgcn_mfma_f32_16x16x32_bf16(af[fm], wf[fn], acc[fm][fn], 0, 0, 0);
  }
#pragma unroll
  for (int fm = 0; fm < 4; ++fm)
#pragma unroll
    for (int fn = 0; fn < 4; ++fn)
#pragma unroll
      for (int r = 0; r < 4; ++r) {
        int row = n0 + fm * 16 + lg * 4 + r;
        int col = m0 + fn * 16 + l15;
        float v = acc[fm][fn][r] + bias[col];
        if (relu) v = fmaxf(v, 0.f);
        if constexpr (CBF) {
          ((u16*)C)[(size_t)row * M + col] = f2bf(v);
        } else {
          if (resid) v += resid[(size_t)row * M + col];
          ((float*)C)[(size_t)row * M + col] = v;
        }
      }
}

// ---------------- LDS-free flash attention ----------------
// All-bf16 inputs. K frags direct global->VGPR; V from pre-transposed vt.
// Swapped QK^T (lane l15 = query); softmax lane-local + shfl(16,32).
// PV: mfma_16x16x16bf16_1k; P already in A-layout. No LDS, no barriers.
__global__ __launch_bounds__(256) void attn_kernel(
    const u16* __restrict__ Q, const u16* __restrict__ Kp,
    const u16* __restrict__ Vt, u16* __restrict__ O,
    int ldq, int ldk, int ldvt, int ldo, int Sq, int Sk, int nqt,
    int qB, int kB, int vB, const int* __restrict__ img, float scale) {
  int tid = threadIdx.x, lane = tid & 63, w = tid >> 6;
  int l15 = lane & 15, lg = lane >> 4;
  int u_ = blockIdx.x;
  int wid = (u_ & 7) * (gridDim.x >> 3) + (u_ >> 3);  // XCD-bijective (grid%8==0)
  int qt = wid % nqt, bh = wid / nqt, h = bh & 7, b = bh >> 3;
  int q_tile = qt * 64 + w * 16;
  const u16* Qb = Q + (size_t)b * qB + h * 32;
  const u16* Kb = Kp + (size_t)b * kB + h * 32;
  const u16* Vb = Vt + (size_t)(h * 32) * ldvt + b * vB;
  u16* Ob = O + (size_t)b * Sq * ldo + h * 32;
  unsigned long long adm = ~0ull;
  if (img) {
    int qimg = img[q_tile >> 9];
    adm = 0;
#pragma unroll
    for (int j = 0; j < 8; ++j)
      if (img[j] == qimg) adm |= (0xFFull << (8 * j));
  }
  bf16x8 qf;
  {
    bf16x8 qr = *(const bf16x8*)(Qb + (size_t)(q_tile + l15) * ldq + lg * 8);
#pragma unroll
    for (int i = 0; i < 8; ++i) qf[i] = (short)f2bf(bf2f((u16)qr[i]) * scale);
  }
  float m_ = -1e30f, l_ = 0.f;
  f32x4 o0 = {}, o1 = {};
  int nc = Sk >> 6;
  for (int c = 0; c < nc; ++c) {
    if (!((adm >> c) & 1)) continue;
    int c0 = c << 6;
    const u16* kbase = Kb + (size_t)c0 * ldk;
    bf16x8 kf[4];
#pragma unroll
    for (int t = 0; t < 4; ++t)
      kf[t] = *(const bf16x8*)(kbase + (size_t)(t * 16 + l15) * ldk + lg * 8);
    const u16* vrow0 = Vb + (size_t)l15 * ldvt + c0;
    const u16* vrow1 = Vb + (size_t)(16 + l15) * ldvt + c0;
    bf16x4 va0[4], va1[4];
#pragma unroll
    for (int t = 0; t < 4; ++t) {
      va0[t] = *(const bf16x4*)(vrow0 + t * 16 + lg * 4);
      va1[t] = *(const bf16x4*)(vrow1 + t * 16 + lg * 4);
    }
    f32x4 z = {};
    f32x4 st[4];
#pragma unroll
    for (int t = 0; t < 4; ++t)
      st[t] = __builtin_amdgcn_mfma_f32_16x16x32_bf16(kf[t], qf, z, 0, 0, 0);
    float cm = st[0][0];
#pragma unroll
    for (int t = 0; t < 4; ++t)
#pragma unroll
      for (int r = 0; r < 4; ++r) cm = fmaxf(cm, st[t][r]);
    cm = fmaxf(cm, __shfl_xor(cm, 16));
    cm = fmaxf(cm, __shfl_xor(cm, 32));
    float mn = fmaxf(m_, cm);
    float sf = __expf(m_ - mn);
    m_ = mn;
    float p[4][4];
    float rs = 0.f;
#pragma unroll
    for (int t = 0; t < 4; ++t)
#pragma unroll
      for (int r = 0; r < 4; ++r) {
        float e = __expf(st[t][r] - mn);
        p[t][r] = e;
        rs += e;
      }
    rs += __shfl_xor(rs, 16);
    rs += __shfl_xor(rs, 32);
    l_ = l_ * sf + rs;
#pragma unroll
    for (int r = 0; r < 4; ++r) {
      float s4 = __shfl(sf, lg * 4 + r);
      o0[r] *= s4;
      o1[r] *= s4;
    }
#pragma unroll
    for (int t = 0; t < 4; ++t) {
      bf16x4 pa;
      pa[0] = (short)f2bf(p[t][0]); pa[1] = (short)f2bf(p[t][1]);
      pa[2] = (short)f2bf(p[t][2]); pa[3] = (short)f2bf(p[t][3]);
      o0 = __builtin_amdgcn_mfma_f32_16x16x16bf16_1k(pa, va0[t], o0, 0, 0, 0);
      o1 = __builtin_amdgcn_mfma_f32_16x16x16bf16_1k(pa, va1[t], o1, 0, 0, 0);
    }
  }
#pragma unroll
  for (int r = 0; r < 4; ++r) {
    float lr = __shfl(l_, lg * 4 + r);
    float inv = 1.f / lr;
    int row = q_tile + lg * 4 + r;
    Ob[(size_t)row * ldo + l15] = f2bf(o0[r] * inv);
    Ob[(size_t)row * ldo + l15 + 16] = f2bf(o1[r] * inv);
  }
}

// ---------------- orchestration ----------------
extern "C" void kernel_launch(void* const* d_in, const int* in_sizes, int n_in,
                              void* d_out, int out_size, void* d_ws, size_t ws_size,
                              hipStream_t stream) {
  const float* curr       = (const float*)d_in[0];
  const float* memory     = (const float*)d_in[1];
  const float* curr_pos   = (const float*)d_in[2];
  const float* memory_pos = (const float*)d_in[3];
  const int*   img_ids    = (const int*)d_in[4];
  const float* sa_w_in  = (const float*)d_in[5];
  const float* sa_b_in  = (const float*)d_in[6];
  const float* sa_w_out = (const float*)d_in[7];
  const float* sa_b_out = (const float*)d_in[8];
  const float* co_w_in  = (const float*)d_in[9];
  const float* co_b_in  = (const float*)d_in[10];
  const float* co_w_out = (const float*)d_in[11];
  const float* co_b_out = (const float*)d_in[12];
  const float* ca_w_in  = (const float*)d_in[13];
  const float* ca_b_in  = (const float*)d_in[14];
  const float* ca_w_out = (const float*)d_in[15];
  const float* ca_b_out = (const float*)d_in[16];
  const float* obj_emb  = (const float*)d_in[17];
  const float* obj_scale= (const float*)d_in[18];
  const float* n1_g = (const float*)d_in[19];
  const float* n1_b = (const float*)d_in[20];
  const float* n2_g = (const float*)d_in[21];
  const float* n2_b = (const float*)d_in[22];
  const float* n3_g = (const float*)d_in[23];
  const float* n3_b = (const float*)d_in[24];
  const float* w1 = (const float*)d_in[25];
  const float* b1 = (const float*)d_in[26];
  const float* w2 = (const float*)d_in[27];
  const float* b2 = (const float*)d_in[28];
  const float* norm_g = (const float*)d_in[29];
  const float* norm_b = (const float*)d_in[30];
  float* out = (float*)d_out;

  char* p = (char*)d_ws;
  float* x    = (float*)p;  p += (size_t)NTOK * DMODEL * 4;
  u16* t2b    = (u16*)p;    p += (size_t)NTOK * DMODEL * 2;
  u16* qkvb   = (u16*)p;    p += (size_t)NTOK * 768 * 2;
  u16* qproj  = (u16*)p;    p += (size_t)NTOK * DMODEL * 2;
  u16* attb   = (u16*)p;    p += (size_t)NTOK * DMODEL * 2;
  u16* memk   = (u16*)p;    p += (size_t)NMEM * DMODEL * 2;
  u16* memv   = (u16*)p;    p += (size_t)NMEM * DMODEL * 2;
  u16* kbufb  = (u16*)p;    p += (size_t)NMEM * DMODEL * 2;
  u16* vbufb  = (u16*)p;    p += (size_t)NMEM * DMODEL * 2;  // aliased as hbuf in MLP
  u16* vtca   = (u16*)p;    p += (size_t)NMEM * DMODEL * 2;
  u16* vtx    = (u16*)p;    p += (size_t)NTOK * DMODEL * 2;
  u16* wbf    = (u16*)p;    p += (size_t)3670016 * 2;
  u16* hbufb  = vbufb;

  const float scale = 0.17677669529663687f;  // 1/sqrt(32)

  // weight bf16 cast (8 segments)
  WArgs wa;
  const float* sp[8] = {sa_w_in, sa_w_out, co_w_in, co_w_out, ca_w_in, ca_w_out, w1, w2};
  int sz[8] = {393216, 131072, 393216, 131072, 393216, 131072, 1048576, 1048576};
  {
    int off = 0;
    for (int j = 0; j < 8; ++j) { wa.src[j] = sp[j]; wa.off[j] = off; wa.n[j] = sz[j]; off += sz[j]; }
  }
  const int O_SA_IN = 0, O_SA_OUT = 393216, O_CO_IN = 524288, O_CO_OUT = 917504;
  const int O_CA_IN = 1048576, O_CA_OUT = 1441792, O_W1 = 1572864, O_W2 = 2621440;

  wcast_kernel<<<512, 256, 0, stream>>>(wa, wbf);
  memprep_kernel<<<2048, 256, 0, stream>>>(memory, memory_pos, memk, memv, NMEM * DMODEL / 8);
  add_kernel<<<1024, 256, 0, stream>>>(curr, curr_pos, 0.1f, x, NTOK * DMODEL / 4);

  for (int l = 0; l < 2; ++l) {
    const u16* w_sa_in  = wbf + O_SA_IN  + l * 196608;
    const u16* w_sa_out = wbf + O_SA_OUT + l * 65536;
    const u16* w_co_in  = wbf + O_CO_IN  + l * 196608;
    const u16* w_co_out = wbf + O_CO_OUT + l * 65536;
    const u16* w_ca_in  = wbf + O_CA_IN  + l * 196608;
    const u16* w_ca_out = wbf + O_CA_OUT + l * 65536;
    const u16* w_1      = wbf + O_W1     + l * 524288;
    const u16* w_2      = wbf + O_W2     + l * 524288;

    // ---- self-attention ----
    ln_kernel<1><<<NTOK, 256, 0, stream>>>(x, n1_g + l * 256, n1_b + l * 256, t2b);
    gemm64_kernel<1><<<dim3(12, 64), 64, 0, stream>>>(t2b, w_sa_in, sa_b_in + l * 768,
                                                      nullptr, qkvb, NTOK, 768, 256, 0);
    transpose_v<<<dim3(64, 8), 256, 0, stream>>>(qkvb, 768, 512, vtx, NTOK);
    attn_kernel<<<512, 256, 0, stream>>>(qkvb, qkvb + 256, vtx, attb,
                                         768, 768, 4096, 256, 512, 512, 8,
                                         512 * 768, 512 * 768, 512, nullptr, scale);
    gemm64_kernel<0><<<dim3(4, 64), 64, 0, stream>>>(attb, w_sa_out, sa_b_out + l * 256,
                                                     x, x, NTOK, 256, 256, 0);
    // ---- cross-object attention (flattened 4096 tokens, image mask) ----
    enh_kernel<<<1024, 256, 0, stream>>>(x, obj_emb + l * 8 * 256, obj_scale + l,
                                         t2b, NTOK * DMODEL / 4);
    gemm64_kernel<1><<<dim3(12, 64), 64, 0, stream>>>(t2b, w_co_in, co_b_in + l * 768,
                                                      nullptr, qkvb, NTOK, 768, 256, 0);
    transpose_v<<<dim3(64, 8), 256, 0, stream>>>(qkvb, 768, 512, vtx, NTOK);
    attn_kernel<<<512, 256, 0, stream>>>(qkvb, qkvb + 256, vtx, attb,
                                         768, 768, 4096, 256, 4096, 4096, 64,
                                         0, 0, 0, img_ids, scale);
    gemm64_kernel<0><<<dim3(4, 64), 64, 0, stream>>>(attb, w_co_out, co_b_out + l * 256,
                                                     x, x, NTOK, 256, 256, 0);
    // ---- cross-attention to memory ----
    ln_kernel<1><<<NTOK, 256, 0, stream>>>(x, n2_g + l * 256, n2_b + l * 256, t2b);
    gemm64_kernel<1><<<dim3(4, 64), 64, 0, stream>>>(t2b, w_ca_in, ca_b_in + l * 768,
                                                     nullptr, qproj, NTOK, 256, 256, 0);
    gemm128_kernel<1><<<dim3(2, 256), 256, 0, stream>>>(memk, w_ca_in + 65536,
                                                        ca_b_in + l * 768 + 256, nullptr,
                                                        kbufb, NMEM, 256, 256, 0);
    gemm128_kernel<1><<<dim3(2, 256), 256, 0, stream>>>(memv, w_ca_in + 131072,
                                                        ca_b_in + l * 768 + 512, nullptr,
                                                        vbufb, NMEM, 256, 256, 0);
    transpose_v<<<dim3(512, 8), 256, 0, stream>>>(vbufb, 256, 0, vtca, NMEM);
    attn_kernel<<<512, 256, 0, stream>>>(qproj, kbufb, vtca, attb,
                                         256, 256, 32768, 256, 512, 4096, 8,
                                         512 * 256, 4096 * 256, 4096, nullptr, scale);
    gemm64_kernel<0><<<dim3(4, 64), 64, 0, stream>>>(attb, w_ca_out, ca_b_out + l * 256,
                                                     x, x, NTOK, 256, 256, 0);
    // ---- MLP ----
    ln_kernel<1><<<NTOK, 256, 0, stream>>>(x, n3_g + l * 256, n3_b + l * 256, t2b);
    gemm128_kernel<1><<<dim3(16, 32), 256, 0, stream>>>(t2b, w_1, b1 + l * 2048, nullptr,
                                                        hbufb, NTOK, 2048, 256, 1);
    gemm64_kernel<0><<<dim3(4, 64), 64, 0, stream>>>(hbufb, w_2, b2 + l * 256,
                                                     x, x, NTOK, 256, 2048, 0);
  }
  ln_kernel<0><<<NTOK, 256, 0, stream>>>(x, norm_g, norm_b, out);
}